// Round 4
// baseline (576.841 us; speedup 1.0000x reference)
//
#include <hip/hip_runtime.h>
#include <math.h>

#define EPSV 1e-6f

namespace {

constexpr int FIN   = 16;
constexpr int FOUT  = 32;
constexpr int BLK   = 256;   // 16 slots (elements) x 16 c-lanes (each owns c, c+16)
constexpr int ELEMS = 16;    // elements per block-iteration
constexpr int GRID  = 768;   // 3 blocks/CU x 256 CUs, exact co-residency

// Cl(3,0), blade order: 1, e1, e2, e3, e12, e13, e23, e123 (masks 0,1,2,4,3,5,6,7).
// GJ[i][k] = output blade index for einsum term with h-blade i, xr-blade k.
constexpr int GJ[8][8] = {
  {0,1,2,3,4,5,6,7},
  {1,0,4,5,2,3,7,6},
  {2,4,0,6,1,7,3,5},
  {3,5,6,0,7,1,2,4},
  {4,2,1,7,0,6,5,3},
  {5,3,7,1,6,0,4,2},
  {6,7,3,2,5,4,0,1},
  {7,6,5,4,3,2,1,0},
};
// Sign: einsum contracts cayley's result axis with xr, outputs right-operand
// axis -> sgn(mask_i, mask_i^mask_k): plain-GP sign, grade-2/3 rows negated.
constexpr float SREF[8][8] = {
  { 1, 1, 1, 1, 1, 1, 1, 1},
  { 1, 1, 1, 1, 1, 1, 1, 1},
  { 1,-1, 1, 1,-1,-1, 1,-1},
  { 1,-1,-1, 1, 1,-1,-1, 1},
  {-1, 1,-1,-1, 1, 1,-1, 1},
  {-1, 1, 1,-1,-1, 1, 1,-1},
  {-1,-1, 1,-1, 1,-1, 1, 1},
  {-1,-1, 1,-1, 1,-1, 1, 1},
};
// 20 distinct (g_i, g_out, g_k) triples; per-thread register cache of gp_w[c].
constexpr int GSLOT[8][8] = {
  {0,1,1,1,2,2,2,3},
  {5,4,7,7,6,6,9,8},
  {5,7,4,7,6,9,6,8},
  {5,7,7,4,9,6,6,8},
  {13,11,11,15,10,14,14,12},
  {13,11,15,11,14,10,14,12},
  {13,15,11,11,14,14,10,12},
  {19,18,18,18,17,17,17,16},
};
constexpr int SLOT_OFF[20] = {0,5,10,15,17,20,22,25,27,30,34,37,39,40,42,45,51,54,57,60};

// bf16 pack (RNE) / unpack helpers
__device__ __forceinline__ unsigned bfp(float a) {
  union { float f; unsigned u; } v; v.f = a;
  return (v.u + 0x7fffu + ((v.u >> 16) & 1u)) >> 16;
}
__device__ __forceinline__ unsigned pk2(float a, float b) {
  return bfp(a) | (bfp(b) << 16);
}
__device__ __forceinline__ float blo(unsigned d) {
  union { unsigned u; float f; } v; v.u = d << 16; return v.f;
}
__device__ __forceinline__ float bhi(unsigned d) {
  union { unsigned u; float f; } v; v.u = d & 0xffff0000u; return v.f;
}

} // namespace

__global__ __launch_bounds__(BLK, 3)
void cge_block_kernel(const float* __restrict__ x,
                      const float* __restrict__ w1,
                      const float* __restrict__ b1,
                      const float* __restrict__ a_relu,
                      const float* __restrict__ b_relu,
                      const float* __restrict__ wl,
                      const float* __restrict__ bl,
                      const float* __restrict__ wr,
                      const float* __restrict__ a_norm,
                      const float* __restrict__ gp_w,
                      const float* __restrict__ a_ln,
                      float* __restrict__ out,
                      int B)
{
  // weights [m][c] fp32 (broadcast reads); activations bf16-packed (8 blades = 16B)
  __shared__ float4 w1s[FIN * FOUT];       // 8 KB
  __shared__ float4 wrs[FOUT * FOUT];      // 16 KB
  __shared__ uint4  xsb[2][ELEMS * FIN];   // 8 KB  bf16 [e][m] double-buffered
  __shared__ uint4  hsb[ELEMS * FOUT];     // 8 KB  bf16 [e][m]

  const int tid  = threadIdx.x;
  const int cidx = tid & 15;
  const int le   = tid >> 4;               // element slot AND x-staging row
  const int c0   = cidx, c1 = cidx + 16;

  // ---- stage weights to LDS (transpose c-major -> m-major) ----
  for (int idx = tid; idx < FIN * FOUT; idx += BLK) {
    int cc = idx >> 4, m = idx & 15;
    w1s[m * FOUT + cc] = ((const float4*)w1)[idx];
  }
  for (int idx = tid; idx < FOUT * FOUT; idx += BLK) {
    int cc = idx >> 5, m = idx & 31;
    wrs[m * FOUT + cc] = ((const float4*)wr)[idx];
  }

  // ---- per-thread constants for both owned channels ----
  float gw[2][20];
  float arr[2][4], brr[2][4], sgg[2][4];
  float b1c[2], blc[2], alnc[2];
  const int cs[2] = {c0, c1};
#pragma unroll
  for (int t = 0; t < 2; ++t) {
    const int c = cs[t];
#pragma unroll
    for (int s = 0; s < 20; ++s) gw[t][s] = gp_w[c * 64 + SLOT_OFF[s]];
    const float4 ar = ((const float4*)a_relu)[c];
    const float4 br = ((const float4*)b_relu)[c];
    const float4 an = ((const float4*)a_norm)[c];
    arr[t][0]=ar.x; arr[t][1]=ar.y; arr[t][2]=ar.z; arr[t][3]=ar.w;
    brr[t][0]=br.x; brr[t][1]=br.y; brr[t][2]=br.z; brr[t][3]=br.w;
    sgg[t][0]=1.f/(1.f+expf(-an.x)); sgg[t][1]=1.f/(1.f+expf(-an.y));
    sgg[t][2]=1.f/(1.f+expf(-an.z)); sgg[t][3]=1.f/(1.f+expf(-an.w));
    b1c[t]=b1[c]; blc[t]=bl[c]; alnc[t]=a_ln[c];
  }
  const float4* wlg = (const float4*)wl;   // wl[c][m], L1-resident
  const float4* xg4 = (const float4*)x;

  const int ngroups = B / ELEMS;
  const int stride  = gridDim.x;
  const int g0      = blockIdx.x;

  // register-double-buffered x prefetch: this thread stages cell (e=le, m=cidx)
  float4 px0, px1;
  auto issue_x = [&](int g) {
    const size_t bi = ((size_t)(g * ELEMS + le) * FIN + cidx) * 2;
    px0 = xg4[bi]; px1 = xg4[bi + 1];
  };

  issue_x(g0 < ngroups ? g0 : 0);
  // prologue: write xsb[0] for first group
  xsb[0][le * FIN + cidx] = make_uint4(pk2(px0.x, px0.y), pk2(px0.z, px0.w),
                                       pk2(px1.x, px1.y), pk2(px1.z, px1.w));
  { int gn = g0 + stride; if (gn >= ngroups) gn = 0; issue_x(gn); }
  __syncthreads();

  int p = 0;
  for (int g = g0; g < ngroups; g += stride, p ^= 1) {
    const int eb = g * ELEMS;

    // ---- phase 1: h = w1 @ x + b1 (x from bf16 LDS, broadcast reads) ----
    float h0[2][8];
#pragma unroll
    for (int t = 0; t < 2; ++t) {
      h0[t][0] = b1c[t];
#pragma unroll
      for (int i = 1; i < 8; ++i) h0[t][i] = 0.f;
    }
#pragma unroll 4
    for (int m = 0; m < FIN; ++m) {
      const uint4 xb = xsb[p][le * FIN + m];
      const float x0 = blo(xb.x), x1 = bhi(xb.x), x2 = blo(xb.y), x3 = bhi(xb.y);
      const float x4 = blo(xb.z), x5 = bhi(xb.z), x6 = blo(xb.w), x7 = bhi(xb.w);
      const float4 wa = w1s[m * FOUT + c0];
      const float4 wb = w1s[m * FOUT + c1];
      h0[0][0] += x0*wa.x; h0[0][1] += x1*wa.y; h0[0][2] += x2*wa.y; h0[0][3] += x3*wa.y;
      h0[0][4] += x4*wa.z; h0[0][5] += x5*wa.z; h0[0][6] += x6*wa.z; h0[0][7] += x7*wa.w;
      h0[1][0] += x0*wb.x; h0[1][1] += x1*wb.y; h0[1][2] += x2*wb.y; h0[1][3] += x3*wb.y;
      h0[1][4] += x4*wb.z; h0[1][5] += x5*wb.z; h0[1][6] += x6*wb.z; h0[1][7] += x7*wb.w;
    }

    // ---- MVReLU gate ----
#pragma unroll
    for (int t = 0; t < 2; ++t) {
      const float q1 = h0[t][1]*h0[t][1] + h0[t][2]*h0[t][2] + h0[t][3]*h0[t][3];
      const float q2 = h0[t][4]*h0[t][4] + h0[t][5]*h0[t][5] + h0[t][6]*h0[t][6];
      const float q3 = h0[t][7]*h0[t][7];
      const float g0v = fmaxf(arr[t][0] * h0[t][0] + brr[t][0], 0.f);
      const float g1v = fmaxf(arr[t][1] * q1 + brr[t][1], 0.f);
      const float g2v = fmaxf(arr[t][2] * q2 + brr[t][2], 0.f);
      const float g3v = fmaxf(arr[t][3] * q3 + brr[t][3], 0.f);
      h0[t][0] *= g0v;
      h0[t][1] *= g1v; h0[t][2] *= g1v; h0[t][3] *= g1v;
      h0[t][4] *= g2v; h0[t][5] *= g2v; h0[t][6] *= g2v;
      h0[t][7] *= g3v;
    }

    // ---- write h (bf16) + next group's x (bf16), prefetch g+2*stride ----
    hsb[le * FOUT + c0] = make_uint4(pk2(h0[0][0], h0[0][1]), pk2(h0[0][2], h0[0][3]),
                                     pk2(h0[0][4], h0[0][5]), pk2(h0[0][6], h0[0][7]));
    hsb[le * FOUT + c1] = make_uint4(pk2(h0[1][0], h0[1][1]), pk2(h0[1][2], h0[1][3]),
                                     pk2(h0[1][4], h0[1][5]), pk2(h0[1][6], h0[1][7]));
    xsb[p ^ 1][le * FIN + cidx] = make_uint4(pk2(px0.x, px0.y), pk2(px0.z, px0.w),
                                             pk2(px1.x, px1.y), pk2(px1.z, px1.w));
    { int gn = g + 2 * stride; if (gn >= ngroups) gn = g0; issue_x(gn); }
    __syncthreads();

    // ---- fused phase 2+3a: xr = wr @ h (LDS) and lin = wl @ h (global/L1) ----
    float xr[2][8], h2[2][8];
#pragma unroll
    for (int t = 0; t < 2; ++t) {
      h2[t][0] = blc[t];
#pragma unroll
      for (int i = 1; i < 8; ++i) h2[t][i] = 0.f;
#pragma unroll
      for (int i = 0; i < 8; ++i) xr[t][i] = 0.f;
    }
#pragma unroll 4
    for (int m = 0; m < FOUT; ++m) {
      const uint4 hb = hsb[le * FOUT + m];
      const float v0 = blo(hb.x), v1 = bhi(hb.x), v2 = blo(hb.y), v3 = bhi(hb.y);
      const float v4 = blo(hb.z), v5 = bhi(hb.z), v6 = blo(hb.w), v7 = bhi(hb.w);
      const float4 wra = wrs[m * FOUT + c0];
      const float4 wrb = wrs[m * FOUT + c1];
      const float4 wla = wlg[c0 * FOUT + m];
      const float4 wlb = wlg[c1 * FOUT + m];
      xr[0][0] += v0*wra.x; xr[0][1] += v1*wra.y; xr[0][2] += v2*wra.y; xr[0][3] += v3*wra.y;
      xr[0][4] += v4*wra.z; xr[0][5] += v5*wra.z; xr[0][6] += v6*wra.z; xr[0][7] += v7*wra.w;
      xr[1][0] += v0*wrb.x; xr[1][1] += v1*wrb.y; xr[1][2] += v2*wrb.y; xr[1][3] += v3*wrb.y;
      xr[1][4] += v4*wrb.z; xr[1][5] += v5*wrb.z; xr[1][6] += v6*wrb.z; xr[1][7] += v7*wrb.w;
      h2[0][0] += v0*wla.x; h2[0][1] += v1*wla.y; h2[0][2] += v2*wla.y; h2[0][3] += v3*wla.y;
      h2[0][4] += v4*wla.z; h2[0][5] += v5*wla.z; h2[0][6] += v6*wla.z; h2[0][7] += v7*wla.w;
      h2[1][0] += v0*wlb.x; h2[1][1] += v1*wlb.y; h2[1][2] += v2*wlb.y; h2[1][3] += v3*wlb.y;
      h2[1][4] += v4*wlb.z; h2[1][5] += v5*wlb.z; h2[1][6] += v6*wlb.z; h2[1][7] += v7*wlb.w;
    }

    // ---- grade-normalize xr ----
#pragma unroll
    for (int t = 0; t < 2; ++t) {
      const float q0 = xr[t][0]*xr[t][0];
      const float q1 = xr[t][1]*xr[t][1] + xr[t][2]*xr[t][2] + xr[t][3]*xr[t][3];
      const float q2 = xr[t][4]*xr[t][4] + xr[t][5]*xr[t][5] + xr[t][6]*xr[t][6];
      const float q3 = xr[t][7]*xr[t][7];
      const float r0 = 1.f / (sgg[t][0] * (sqrtf(q0) - 1.f) + 1.f + EPSV);
      const float r1 = 1.f / (sgg[t][1] * (sqrtf(q1) - 1.f) + 1.f + EPSV);
      const float r2 = 1.f / (sgg[t][2] * (sqrtf(q2) - 1.f) + 1.f + EPSV);
      const float r3 = 1.f / (sgg[t][3] * (sqrtf(q3) - 1.f) + 1.f + EPSV);
      xr[t][0] *= r0;
      xr[t][1] *= r1; xr[t][2] *= r1; xr[t][3] *= r1;
      xr[t][4] *= r2; xr[t][5] *= r2; xr[t][6] *= r2;
      xr[t][7] *= r3;
    }

    // ---- sparse steerable GP (registers; h0 full fp32) ----
#pragma unroll
    for (int i = 0; i < 8; ++i) {
#pragma unroll
      for (int k = 0; k < 8; ++k) {
        const int j = GJ[i][k], s = GSLOT[i][k];
        h2[0][j] += (SREF[i][k] * gw[0][s] * h0[0][i]) * xr[0][k];
        h2[1][j] += (SREF[i][k] * gw[1][s] * h0[1][i]) * xr[1][k];
      }
    }

    // ---- 1/sqrt(2), MVLayerNorm over 32 channels (16-lane shuffle), store ----
    float s = 0.f;
#pragma unroll
    for (int t = 0; t < 2; ++t) {
      float q = 0.f;
#pragma unroll
      for (int i = 0; i < 8; ++i) {
        h2[t][i] *= 0.70710678118654752f;
        q += h2[t][i] * h2[t][i];
      }
      s += sqrtf(q);
    }
    s += __shfl_xor(s, 1);
    s += __shfl_xor(s, 2);
    s += __shfl_xor(s, 4);
    s += __shfl_xor(s, 8);     // sum over the 16 cidx lanes of this slot
    const float nrm = s * (1.f / FOUT) + EPSV;
    float4* o4 = (float4*)out + (size_t)(eb + le) * (FOUT * 2);
#pragma unroll
    for (int t = 0; t < 2; ++t) {
      const float sc = alnc[t] / nrm;
      o4[cs[t] * 2]     = make_float4(h2[t][0]*sc, h2[t][1]*sc, h2[t][2]*sc, h2[t][3]*sc);
      o4[cs[t] * 2 + 1] = make_float4(h2[t][4]*sc, h2[t][5]*sc, h2[t][6]*sc, h2[t][7]*sc);
    }
    __syncthreads();
  }
}

extern "C" void kernel_launch(void* const* d_in, const int* in_sizes, int n_in,
                              void* d_out, int out_size, void* d_ws, size_t ws_size,
                              hipStream_t stream) {
  const float* x      = (const float*)d_in[0];
  const float* w1     = (const float*)d_in[1];
  const float* b1     = (const float*)d_in[2];
  const float* a_relu = (const float*)d_in[3];
  const float* b_relu = (const float*)d_in[4];
  const float* wl     = (const float*)d_in[5];
  const float* bl     = (const float*)d_in[6];
  const float* wr     = (const float*)d_in[7];
  const float* a_norm = (const float*)d_in[8];
  const float* gp_w   = (const float*)d_in[9];
  const float* a_ln   = (const float*)d_in[10];
  // d_in[11] = cayley — fixed for Cl(3,0); tables are baked in.

  const int B = in_sizes[0] / (FIN * 8);       // 131072
  const int ngroups = B / ELEMS;
  const int grid = ngroups < GRID ? ngroups : GRID;

  cge_block_kernel<<<grid, BLK, 0, stream>>>(
      x, w1, b1, a_relu, b_relu, wl, bl, wr, a_norm, gp_w, a_ln,
      (float*)d_out, B);
}